// Round 4
// baseline (426.755 us; speedup 1.0000x reference)
//
#include <hip/hip_runtime.h>

typedef unsigned short u16;
typedef __bf16 bf16x8 __attribute__((ext_vector_type(8)));   // gfx950 MFMA A/B fragment
typedef float f32x4 __attribute__((ext_vector_type(4)));

__device__ __forceinline__ float b2f(u16 u) {
    unsigned int x = ((unsigned int)u) << 16;
    float f; __builtin_memcpy(&f, &x, 4); return f;
}
__device__ __forceinline__ u16 f2b(float f) {
    unsigned int x; __builtin_memcpy(&x, &f, 4);
    unsigned int r = (x + 0x7fffu + ((x >> 16) & 1u)) >> 16;
    return (u16)r;
}

// ---------------------------------------------------------------------------
// k_prep: fp32 weights -> bf16, permuted into tap-major K order (r = tap*64+ci).
//   blk <  2048 : wv_om row m = c*32 + q, q = j*9+k (j=0 offy,1 offx,2 msk),
//                 q in [27,32) zero pad. src row: j<2 ? (c*9+k)*2+j : 1152+c*9+k
//   blk in [2048,2112): wv_in row (K-order permute)
//   blk in [2112,2176): wv_dc row (native order ci*9+tap kept: matches mod_t)
// Biases stored as f32 (bv_om, bv_dc).
// ---------------------------------------------------------------------------
__global__ void k_prep(const float* __restrict__ w_om, const float* __restrict__ b_om,
                       const float* __restrict__ w_in, const float* __restrict__ w_dc,
                       const float* __restrict__ b_dc,
                       u16* __restrict__ wv_om, float* __restrict__ bv_om,
                       u16* __restrict__ wv_in, u16* __restrict__ wv_dc,
                       float* __restrict__ bv_dc)
{
    int blk = blockIdx.x, t = threadIdx.x;
    if (blk < 2048) {
        int m = blk, c = m >> 5, q = m & 31;
        bool pad = q >= 27;
        int src = 0;
        if (!pad) { int j = q / 9, k = q - j * 9; src = (j < 2) ? ((c * 9 + k) * 2 + j) : (1152 + c * 9 + k); }
        for (int idx = t; idx < 576; idx += 128) {
            int tap = idx >> 6, ci = idx & 63;
            wv_om[(size_t)m * 576 + idx] = pad ? (u16)0 : f2b(w_om[(size_t)src * 576 + ci * 9 + tap]);
        }
        if (t == 0) bv_om[m] = pad ? 0.f : b_om[src];
    } else if (blk < 2112) {
        int m = blk - 2048;
        for (int idx = t; idx < 576; idx += 128) {
            int tap = idx >> 6, ci = idx & 63;
            wv_in[(size_t)m * 576 + idx] = f2b(w_in[(size_t)m * 576 + ci * 9 + tap]);
        }
    } else {
        int m = blk - 2112;
        for (int idx = t; idx < 576; idx += 128)
            wv_dc[(size_t)m * 576 + idx] = f2b(w_dc[(size_t)m * 576 + idx]);
        if (t == 0) bv_dc[m] = b_dc[m];
    }
}

// ---------------------------------------------------------------------------
// k_transpose: x NCHW fp32 -> x_t padded NHWC bf16 [b][y+1 (130)][x+1 (130)][ci]
// one block per (b,y) row.  Borders pre-zeroed by memset.
// ---------------------------------------------------------------------------
__global__ void k_transpose(const float* __restrict__ x, u16* __restrict__ x_t)
{
    __shared__ u16 sm[64 * 136];            // rows padded to 136
    int row = blockIdx.x;
    int b = row >> 7, y = row & 127;
    int t = threadIdx.x;
    for (int it = 0; it < 4; ++it) {
        int chunk = it * 256 + t;           // 1024 chunks of 8 floats
        int ci = chunk >> 4, part = chunk & 15;
        const float4* src = (const float4*)(x + (((size_t)(b * 64 + ci) * 128 + y) * 128) + part * 8);
        float4 v0 = src[0], v1 = src[1];
        u16 tmp[8] = { f2b(v0.x), f2b(v0.y), f2b(v0.z), f2b(v0.w),
                       f2b(v1.x), f2b(v1.y), f2b(v1.z), f2b(v1.w) };
        *(uint4*)(&sm[ci * 136 + part * 8]) = *(uint4*)tmp;
    }
    __syncthreads();
    int xx = t >> 1, half = t & 1;
    u16 tmp[32];
#pragma unroll
    for (int cc = 0; cc < 32; ++cc) tmp[cc] = sm[(half * 32 + cc) * 136 + xx];
    u16* dst = x_t + (((size_t)(b * 130) + y + 1) * 130 + (xx + 1)) * 64 + half * 32;
#pragma unroll
    for (int j = 0; j < 4; ++j) ((uint4*)dst)[j] = ((uint4*)tmp)[j];
}

// ---------------------------------------------------------------------------
// k_conv1: feat = leaky_relu(conv3x3(x) + b_in).  GEMM [64,576]x[576,128] per row.
// Writes feat_t (padded NHWC bf16) and feat_c (CNHW bf16).
// ---------------------------------------------------------------------------
__global__ __launch_bounds__(256) void k_conv1(
    const u16* __restrict__ wv_in, const float* __restrict__ b_in,
    const u16* __restrict__ x_t, u16* __restrict__ feat_t, u16* __restrict__ feat_c)
{
    __shared__ char smem[33792];            // gemm: A 8KB @0, B 16KB @8192 ; epi: f32 om[64][132]
    float* om = (float*)smem;
    int row = blockIdx.x, b = row >> 7, y = row & 127;
    int t = threadIdx.x, lane = t & 63, wv = t >> 6;
    int wm = wv >> 1, wn = wv & 1, lm = lane & 15, kg = lane >> 4;
    f32x4 acc[2][4] = {};
    const u16* fb = x_t + (size_t)b * 130 * 130 * 64;
    for (int tap = 0; tap < 9; ++tap) {
        int dy = tap / 3, dx = tap - dy * 3;
        // A: 8 slots of 64x16B, wave does 2.  slot s = r2*64 + m
        for (int ii = 0; ii < 2; ++ii) {
            int i = wv * 2 + ii;            // i == r2
            *(uint4*)(smem + i * 1024 + lane * 16) =
                *(const uint4*)(wv_in + (size_t)lane * 576 + tap * 64 + i * 8);
        }
        // B: 16 slots, wave does 4. slot s = r2*128 + n
        for (int ii = 0; ii < 4; ++ii) {
            int i = wv * 4 + ii;
            int n = ((i & 1) << 6) | lane, r2 = i >> 1;
            *(uint4*)(smem + 8192 + i * 1024 + lane * 16) =
                *(const uint4*)(fb + ((size_t)(y + dy) * 130 + dx + n) * 64 + r2 * 8);
        }
        __syncthreads();
#pragma unroll
        for (int ks = 0; ks < 2; ++ks) {
            bf16x8 af[2], bf[4];
            int run = ks * 4 + kg;
#pragma unroll
            for (int mt = 0; mt < 2; ++mt)
                af[mt] = *(const bf16x8*)(smem + (run * 64 + wm * 32 + mt * 16 + lm) * 16);
#pragma unroll
            for (int nt = 0; nt < 4; ++nt)
                bf[nt] = *(const bf16x8*)(smem + 8192 + (run * 128 + wn * 64 + nt * 16 + lm) * 16);
#pragma unroll
            for (int mt = 0; mt < 2; ++mt)
#pragma unroll
                for (int nt = 0; nt < 4; ++nt)
                    acc[mt][nt] = __builtin_amdgcn_mfma_f32_16x16x32_bf16(af[mt], bf[nt], acc[mt][nt], 0, 0, 0);
        }
        __syncthreads();
    }
    // epilogue: bias + leaky relu, dump to LDS f32 [64][132]
#pragma unroll
    for (int mt = 0; mt < 2; ++mt)
#pragma unroll
        for (int nt = 0; nt < 4; ++nt)
#pragma unroll
            for (int i = 0; i < 4; ++i) {
                int m = wm * 32 + mt * 16 + kg * 4 + i;
                int n = wn * 64 + nt * 16 + lm;
                float v = acc[mt][nt][i] + b_in[m];
                v = v > 0.f ? v : 0.1f * v;
                om[m * 132 + n] = v;
            }
    __syncthreads();
    // feat_c [ci][b][y][x]
    for (int it = 0; it < 32; ++it) {
        int item = it * 256 + t, ci = item >> 7, xx = item & 127;
        feat_c[(((size_t)(ci * 2 + b)) * 128 + y) * 128 + xx] = f2b(om[ci * 132 + xx]);
    }
    // feat_t padded NHWC
    {
        int xx = t >> 1, half = t & 1;
        u16 tmp[32];
#pragma unroll
        for (int cc = 0; cc < 32; ++cc) tmp[cc] = f2b(om[(half * 32 + cc) * 132 + xx]);
        u16* dst = feat_t + (((size_t)(b * 130) + y + 1) * 130 + (xx + 1)) * 64 + half * 32;
#pragma unroll
        for (int j = 0; j < 4; ++j) ((uint4*)dst)[j] = ((uint4*)tmp)[j];
    }
}

// ---------------------------------------------------------------------------
// k_conv2: offset/mask conv (GEMM [128,576]x[576,128]) + sigmoid + bilinear
// sampling + mask modulation, writing mod_t[p][c*9+k] bf16.
// grid: (g = c-group 0..15, row = b*128+y)
// Epilogue om compact: only q = m&31 < 27 rows (108 rows) -> 57 KB LDS <= 64 KB.
// ---------------------------------------------------------------------------
__global__ __launch_bounds__(256) void k_conv2(
    const u16* __restrict__ wv_om, const float* __restrict__ bv_om,
    const u16* __restrict__ feat_t, const u16* __restrict__ feat_c,
    u16* __restrict__ mod_t)
{
    __shared__ char smem[57024];            // gemm: A 16KB @0, B 16KB @16384 ; epi: f32 om[108][132]
    float* om = (float*)smem;
    int g = blockIdx.x, row = blockIdx.y;
    int b = row >> 7, y = row & 127;
    int t = threadIdx.x, lane = t & 63, wv = t >> 6;
    int wm = wv >> 1, wn = wv & 1, lm = lane & 15, kg = lane >> 4;
    f32x4 acc[4][4] = {};
    const u16* wb = wv_om + (size_t)g * 128 * 576;
    const u16* fb = feat_t + (size_t)b * 130 * 130 * 64;
    for (int tap = 0; tap < 9; ++tap) {
        int dy = tap / 3, dx = tap - dy * 3;
        for (int ii = 0; ii < 4; ++ii) {
            int i = wv * 4 + ii;
            int mm = ((i & 1) << 6) | lane, r2 = i >> 1;
            *(uint4*)(smem + i * 1024 + lane * 16) =
                *(const uint4*)(wb + (size_t)mm * 576 + tap * 64 + r2 * 8);
            *(uint4*)(smem + 16384 + i * 1024 + lane * 16) =
                *(const uint4*)(fb + ((size_t)(y + dy) * 130 + dx + mm) * 64 + r2 * 8);
        }
        __syncthreads();
#pragma unroll
        for (int ks = 0; ks < 2; ++ks) {
            bf16x8 af[4], bf[4];
            int run = ks * 4 + kg;
#pragma unroll
            for (int mt = 0; mt < 4; ++mt)
                af[mt] = *(const bf16x8*)(smem + (run * 128 + wm * 64 + mt * 16 + lm) * 16);
#pragma unroll
            for (int nt = 0; nt < 4; ++nt)
                bf[nt] = *(const bf16x8*)(smem + 16384 + (run * 128 + wn * 64 + nt * 16 + lm) * 16);
#pragma unroll
            for (int mt = 0; mt < 4; ++mt)
#pragma unroll
                for (int nt = 0; nt < 4; ++nt)
                    acc[mt][nt] = __builtin_amdgcn_mfma_f32_16x16x32_bf16(af[mt], bf[nt], acc[mt][nt], 0, 0, 0);
        }
        __syncthreads();
    }
    // dump om tile (with bias) to LDS f32, compact rows: m -> cl*27 + q (q<27 only)
#pragma unroll
    for (int mt = 0; mt < 4; ++mt)
#pragma unroll
        for (int nt = 0; nt < 4; ++nt)
#pragma unroll
            for (int i = 0; i < 4; ++i) {
                int m = wm * 64 + mt * 16 + kg * 4 + i;
                int q = m & 31, cl = m >> 5;
                if (q < 27) {
                    int n = wn * 64 + nt * 16 + lm;
                    om[(cl * 27 + q) * 132 + n] = acc[mt][nt][i] + bv_om[g * 128 + m];
                }
            }
    __syncthreads();
    // sampling: 4 c's * 9 k * 128 x = 4608 items
    for (int it = 0; it < 18; ++it) {
        int item = it * 256 + t;
        int ckl = item >> 7, xx = item & 127;
        int cl = ckl / 9, k = ckl - cl * 9;
        float offy = om[(cl * 27 + k) * 132 + xx];
        float offx = om[(cl * 27 + 9 + k) * 132 + xx];
        float mv   = om[(cl * 27 + 18 + k) * 132 + xx];
        float msk = 1.f / (1.f + __expf(-mv));
        float py = (float)(y + k / 3 - 1) + offy;
        float px = (float)(xx + (k - (k / 3) * 3) - 1) + offx;
        float y0f = floorf(py), x0f = floorf(px);
        int y0 = (int)y0f, x0 = (int)x0f;
        float wy = py - y0f, wx = px - x0f;
        int c = g * 4 + cl;
        const u16* f = feat_c + ((size_t)(c * 2 + b)) * (128 * 128);
        float v00 = ((unsigned)y0 < 128u && (unsigned)x0 < 128u) ? b2f(f[y0 * 128 + x0]) : 0.f;
        float v01 = ((unsigned)y0 < 128u && (unsigned)(x0 + 1) < 128u) ? b2f(f[y0 * 128 + x0 + 1]) : 0.f;
        float v10 = ((unsigned)(y0 + 1) < 128u && (unsigned)x0 < 128u) ? b2f(f[(y0 + 1) * 128 + x0]) : 0.f;
        float v11 = ((unsigned)(y0 + 1) < 128u && (unsigned)(x0 + 1) < 128u) ? b2f(f[(y0 + 1) * 128 + x0 + 1]) : 0.f;
        float s = (1.f - wy) * ((1.f - wx) * v00 + wx * v01) + wy * ((1.f - wx) * v10 + wx * v11);
        mod_t[((size_t)row * 128 + xx) * 576 + c * 9 + k] = f2b(s * msk);
    }
}

// ---------------------------------------------------------------------------
// k_gemm3: out = relu(wv_dc[64,576] x mod_t^T + b_dc), fp32 NCHW out.
// (wv_dc layout o*576 + ci*9 + tap matches mod_t's K-order c*9+k directly.)
// ---------------------------------------------------------------------------
__global__ __launch_bounds__(256) void k_gemm3(
    const u16* __restrict__ wv_dc, const float* __restrict__ bv_dc,
    const u16* __restrict__ mod_t, float* __restrict__ out)
{
    __shared__ char smem[24576];            // A 8KB @0, B 16KB @8192
    int row = blockIdx.x, b = row >> 7, y = row & 127;
    int t = threadIdx.x, lane = t & 63, wv = t >> 6;
    int wm = wv >> 1, wn = wv & 1, lm = lane & 15, kg = lane >> 4;
    f32x4 acc[2][4] = {};
    size_t p0 = (size_t)row * 128;
    for (int kc = 0; kc < 9; ++kc) {
        for (int ii = 0; ii < 2; ++ii) {
            int i = wv * 2 + ii;
            *(uint4*)(smem + i * 1024 + lane * 16) =
                *(const uint4*)(wv_dc + (size_t)lane * 576 + kc * 64 + i * 8);
        }
        for (int ii = 0; ii < 4; ++ii) {
            int i = wv * 4 + ii;
            int n = ((i & 1) << 6) | lane, r2 = i >> 1;
            *(uint4*)(smem + 8192 + i * 1024 + lane * 16) =
                *(const uint4*)(mod_t + (p0 + n) * 576 + kc * 64 + r2 * 8);
        }
        __syncthreads();
#pragma unroll
        for (int ks = 0; ks < 2; ++ks) {
            bf16x8 af[2], bf[4];
            int run = ks * 4 + kg;
#pragma unroll
            for (int mt = 0; mt < 2; ++mt)
                af[mt] = *(const bf16x8*)(smem + (run * 64 + wm * 32 + mt * 16 + lm) * 16);
#pragma unroll
            for (int nt = 0; nt < 4; ++nt)
                bf[nt] = *(const bf16x8*)(smem + 8192 + (run * 128 + wn * 64 + nt * 16 + lm) * 16);
#pragma unroll
            for (int mt = 0; mt < 2; ++mt)
#pragma unroll
                for (int nt = 0; nt < 4; ++nt)
                    acc[mt][nt] = __builtin_amdgcn_mfma_f32_16x16x32_bf16(af[mt], bf[nt], acc[mt][nt], 0, 0, 0);
        }
        __syncthreads();
    }
#pragma unroll
    for (int mt = 0; mt < 2; ++mt)
#pragma unroll
        for (int nt = 0; nt < 4; ++nt)
#pragma unroll
            for (int i = 0; i < 4; ++i) {
                int o = wm * 32 + mt * 16 + kg * 4 + i;
                int n = wn * 64 + nt * 16 + lm;
                float v = acc[mt][nt][i] + bv_dc[o];
                v = v > 0.f ? v : 0.f;
                out[(((size_t)(b * 64 + o)) * 128 + y) * 128 + n] = v;
            }
}

// ---------------------------------------------------------------------------
// workspace layout (bytes):
//   x_t    @ 0         : 4,326,400      (bf16, padded NHWC)
//   feat_t @ 4326400   : 4,326,400
//   feat_c @ 8652800   : 4,194,304
//   wv_om  @ 12847104  : 2,359,296
//   wv_in  @ 15206400  : 73,728
//   wv_dc  @ 15280128  : 73,728
//   bv_om  @ 15353856  : 8,192  (f32)
//   bv_dc  @ 15362048  : 256    (f32)
//   mod_t  @ 15362304  : 37,748,736   (end ~53.1 MB; prior rounds wrote this
//                                      range with clean syncs -> ws is big enough)
// ---------------------------------------------------------------------------
extern "C" void kernel_launch(void* const* d_in, const int* in_sizes, int n_in,
                              void* d_out, int out_size, void* d_ws, size_t ws_size,
                              hipStream_t stream)
{
    (void)in_sizes; (void)n_in; (void)out_size; (void)ws_size;
    const float* x    = (const float*)d_in[0];
    const float* w_in = (const float*)d_in[1];
    const float* b_in = (const float*)d_in[2];
    const float* w_om = (const float*)d_in[3];
    const float* b_om = (const float*)d_in[4];
    const float* w_dc = (const float*)d_in[5];
    const float* b_dc = (const float*)d_in[6];
    char* ws = (char*)d_ws;
    u16*   x_t    = (u16*)(ws);
    u16*   feat_t = (u16*)(ws + 4326400);
    u16*   feat_c = (u16*)(ws + 8652800);
    u16*   wv_om  = (u16*)(ws + 12847104);
    u16*   wv_in  = (u16*)(ws + 15206400);
    u16*   wv_dc  = (u16*)(ws + 15280128);
    float* bv_om  = (float*)(ws + 15353856);
    float* bv_dc  = (float*)(ws + 15362048);
    u16*   mod_t  = (u16*)(ws + 15362304);

    hipMemsetAsync(ws, 0, 8652800, stream);   // zero x_t + feat_t (conv zero-padding)
    hipLaunchKernelGGL(k_prep, dim3(2176), dim3(128), 0, stream,
                       w_om, b_om, w_in, w_dc, b_dc, wv_om, bv_om, wv_in, wv_dc, bv_dc);
    hipLaunchKernelGGL(k_transpose, dim3(256), dim3(256), 0, stream, x, x_t);
    hipLaunchKernelGGL(k_conv1, dim3(256), dim3(256), 0, stream,
                       wv_in, b_in, x_t, feat_t, feat_c);
    hipLaunchKernelGGL(k_conv2, dim3(16, 256), dim3(256), 0, stream,
                       wv_om, bv_om, feat_t, feat_c, mod_t);
    hipLaunchKernelGGL(k_gemm3, dim3(256), dim3(256), 0, stream,
                       wv_dc, bv_dc, mod_t, (float*)d_out);
}